// Round 15
// baseline (517.285 us; speedup 1.0000x reference)
//
#include <hip/hip_runtime.h>
#include <hip/hip_bf16.h>

typedef __attribute__((ext_vector_type(8))) short bf16x8v;
typedef __attribute__((ext_vector_type(4))) float f32x4v;

#define DEV __device__ __forceinline__

constexpr int Bn = 8, Sn = 4096, En = 512, Hn = 512;
constexpr int Mn = Bn * Sn;          // 32768 rows
constexpr int NCc = 128, CHc = 32;   // scan: 128 chunks of 32
constexpr size_t SLOT = 33579008;    // = 8*4099*512*2 bytes (padded-conv buffer), 4096-aligned

// ---------- math helpers ----------
DEV float bfu(unsigned u){ union{unsigned v; float f;} c; c.v = u << 16; return c.f; }

DEV void gload16(const void* g, void* l){
  __builtin_amdgcn_global_load_lds((const __attribute__((address_space(1))) void*)g,
                                   (__attribute__((address_space(3))) void*)l, 16, 0, 0);
}

// linear-space gates: f' = (1+e^-i)/(2+e^-f+e^-i), i' = (1+e^-f)/(...), g = x>=0? x+.5 : sigmoid(x)
DEV void gate_lin(float f, float i, float hp, float& fp, float& ig){
  const float ef = __expf(-f);
  const float ei = __expf(-i);
  const float rd = 1.f / (2.f + ef + ei);
  fp = (1.f + ei) * rd;
  const float ipv = (1.f + ef) * rd;
  const float g = (hp >= 0.f) ? (hp + 0.5f) : (1.f / (1.f + __expf(-hp)));
  ig = ipv * g;
}

DEV float g_of(float x){ return (x >= 0.f) ? (x + 0.5f) : (1.f / (1.f + __expf(-x))); }

// ---------- bf16 MFMA GEMM, 256x256 tile, BK=64, 8 waves (2Mx4N), 512 thr ----------
// r14's coalesced staging (4 lanes per 64B row-line, involutive chunk-XOR on
// both write-source and read-address) + r12's FRAGMENT DOUBLE-BUFFER loop:
// phase p's MFMA consumes regs loaded during phase p-1 while p issues the
// ds_reads for p+1 — overlapping the two serial components measured at r14
// (LDS fragment drain ~578cy, MFMA pipe ~620cy per phase). One barrier/phase.
// vmcnt(4) at p1/p3: at p3 the 4 oldest outstanding loads are nxt's K0 units,
// so the cross-buffer prefetch after p3's barrier is RAW-safe. r10-13's nulls
// were re-attributed to the staging request-rate bound (fixed in r14), so this
// is the first test of frag-dbuf in the visible regime.
// C[M,N] = A(row-mapped)[M,K] * Bw[N,K]^T + bias
// RES: 0 none, 1 add bf16 residual at res[r*rRS + (r>>12)*rBP + rOff + c]
template<int RES, bool RELU, bool OUTF32>
__global__ __launch_bounds__(512, 1)
void gemm_bf16(const __hip_bfloat16* __restrict__ A,
               const __hip_bfloat16* __restrict__ Bw,
               int N, int K, int aRS, int aBP,
               const float* __restrict__ bias,
               const __hip_bfloat16* __restrict__ res, int rRS, int rBP, int rOff,
               void* __restrict__ out)
{
  __shared__ __align__(16) __hip_bfloat16 Al[2][2][256][32];   // [buf][Kh][row][k] 64 KB
  __shared__ __align__(16) __hip_bfloat16 Bl[2][2][256][32];   // 64 KB
  const int tid  = threadIdx.x;
  const int lane = tid & 63;
  const int w    = tid >> 6;            // 0..7
  const int ntn  = N >> 8;
  // T1: XCD-aware bijective swizzle (all grids are multiples of 8)
  const int nwg = gridDim.x;
  int wg = blockIdx.x;
  if ((nwg & 7) == 0) wg = ((wg & 7) * (nwg >> 3)) + (wg >> 3);
  const int bm = wg / ntn, bn = wg % ntn;
  const int rowBase = bm << 8, colBase = bn << 8;
  const int wm = w >> 2, wn = w & 3;    // 2 x 4 wave grid
  const int r0 = lane & 15, kc = lane >> 4;
  const int xk = (r0 >> 1) & 3;         // read-side XOR key
  const int rc = (kc ^ xk) << 3;        // element offset of fragment within [32k] row

  f32x4v acc[8][4];
  #pragma unroll
  for (int i=0;i<8;i++)
    #pragma unroll
    for (int j=0;j<4;j++)
      #pragma unroll
      for (int q=0;q<4;q++) acc[i][j][q] = 0.f;

  // staging slots: s=(j<<9)+tid; row=s>>2, cp=s&3, src chunk = cp^((row>>1)&3)
  int sr[2], scp[2];
  size_t aoff[2], boff[2];
  #pragma unroll
  for (int j=0;j<2;j++){
    const int s  = (j<<9) + tid;        // 0..1023
    const int r  = s >> 2;
    const int cp = s & 3;
    const int cs = cp ^ ((r >> 1) & 3);
    sr[j] = r; scp[j] = cp;
    const int rowg = rowBase + r;
    aoff[j] = (size_t)rowg*aRS + (size_t)(rowg>>12)*aBP + (cs<<3);
    boff[j] = (size_t)(colBase + r)*K + (cs<<3);
  }

  // unit: 0=A-K0, 1=B-K0, 2=A-K1, 3=B-K1  (issue order matters for vmcnt math)
  auto stage_unit = [&](int buf, int unit, int t){
    const int Kh = unit >> 1;
    const int ke = (t<<6) + (Kh<<5);
    if ((unit & 1) == 0){
      #pragma unroll
      for (int j=0;j<2;j++) gload16(A  + aoff[j] + ke, &Al[buf][Kh][sr[j]][scp[j]<<3]);
    } else {
      #pragma unroll
      for (int j=0;j<2;j++) gload16(Bw + boff[j] + ke, &Bl[buf][Kh][sr[j]][scp[j]<<3]);
    }
  };

  const int NT = K >> 6;           // 8 (K=512) or 32 (K=2048)

  // prologue: stage all 4 units of tile 0; K0 units must land
  stage_unit(0,0,0); stage_unit(0,1,0); stage_unit(0,2,0); stage_unit(0,3,0);
  asm volatile("s_waitcnt vmcnt(4)" ::: "memory");
  __builtin_amdgcn_s_barrier();

  // frag preload: a0 = A(h0,K0), bv0 = B(K0)
  bf16x8v a0[4], a1[4], bv0[4], bv1[4];
  #pragma unroll
  for (int ni=0;ni<4;ni++) bv0[ni] = *(const bf16x8v*)&Bl[0][0][(wn<<6)+(ni<<4)+r0][rc];
  #pragma unroll
  for (int m=0;m<4;m++)    a0[m]  = *(const bf16x8v*)&Al[0][0][(wm<<7)+(m<<4)+r0][rc];
  asm volatile("s_waitcnt lgkmcnt(0)" ::: "memory");

  for (int t=0; t<NT; t++){
    const int cur = t & 1, nxt = cur ^ 1;
    const bool pre = (t+1 < NT);
    // ---------- p0: MFMA(a0,bv0)->acc[0..3]; prefetch a1 = A(h1,K0)
    if (pre) stage_unit(nxt, 0, t+1);
    __builtin_amdgcn_s_barrier();
    #pragma unroll
    for (int m=0;m<4;m++) a1[m] = *(const bf16x8v*)&Al[cur][0][(wm<<7)+((4+m)<<4)+r0][rc];
    __builtin_amdgcn_sched_barrier(0);
    __builtin_amdgcn_s_setprio(1);
    #pragma unroll
    for (int m=0;m<4;m++)
      #pragma unroll
      for (int ni=0;ni<4;ni++)
        acc[m][ni] = __builtin_amdgcn_mfma_f32_16x16x32_bf16(a0[m], bv0[ni], acc[m][ni], 0, 0, 0);
    __builtin_amdgcn_s_setprio(0);
    asm volatile("s_waitcnt lgkmcnt(0)" ::: "memory");
    // ---------- p1: MFMA(a1,bv0)->acc[4..7]; prefetch a0 = A(h0,K1), bv1 = B(K1)
    if (pre){ stage_unit(nxt, 1, t+1);
              asm volatile("s_waitcnt vmcnt(4)" ::: "memory"); }
    else      asm volatile("s_waitcnt vmcnt(0)" ::: "memory");
    __builtin_amdgcn_s_barrier();
    #pragma unroll
    for (int ni=0;ni<4;ni++) bv1[ni] = *(const bf16x8v*)&Bl[cur][1][(wn<<6)+(ni<<4)+r0][rc];
    #pragma unroll
    for (int m=0;m<4;m++)    a0[m]  = *(const bf16x8v*)&Al[cur][1][(wm<<7)+(m<<4)+r0][rc];
    __builtin_amdgcn_sched_barrier(0);
    __builtin_amdgcn_s_setprio(1);
    #pragma unroll
    for (int m=0;m<4;m++)
      #pragma unroll
      for (int ni=0;ni<4;ni++)
        acc[4+m][ni] = __builtin_amdgcn_mfma_f32_16x16x32_bf16(a1[m], bv0[ni], acc[4+m][ni], 0, 0, 0);
    __builtin_amdgcn_s_setprio(0);
    asm volatile("s_waitcnt lgkmcnt(0)" ::: "memory");
    // ---------- p2: MFMA(a0,bv1)->acc[0..3]; prefetch a1 = A(h1,K1)
    if (pre) stage_unit(nxt, 2, t+1);
    __builtin_amdgcn_s_barrier();
    #pragma unroll
    for (int m=0;m<4;m++) a1[m] = *(const bf16x8v*)&Al[cur][1][(wm<<7)+((4+m)<<4)+r0][rc];
    __builtin_amdgcn_sched_barrier(0);
    __builtin_amdgcn_s_setprio(1);
    #pragma unroll
    for (int m=0;m<4;m++)
      #pragma unroll
      for (int ni=0;ni<4;ni++)
        acc[m][ni] = __builtin_amdgcn_mfma_f32_16x16x32_bf16(a0[m], bv1[ni], acc[m][ni], 0, 0, 0);
    __builtin_amdgcn_s_setprio(0);
    asm volatile("s_waitcnt lgkmcnt(0)" ::: "memory");
    // ---------- p3: MFMA(a1,bv1)->acc[4..7]; prefetch a0,bv0 from nxt buffer
    if (pre){ stage_unit(nxt, 3, t+1);
              asm volatile("s_waitcnt vmcnt(4)" ::: "memory"); }
    else      asm volatile("s_waitcnt vmcnt(0)" ::: "memory");
    __builtin_amdgcn_s_barrier();
    if (pre){
      #pragma unroll
      for (int ni=0;ni<4;ni++) bv0[ni] = *(const bf16x8v*)&Bl[nxt][0][(wn<<6)+(ni<<4)+r0][rc];
      #pragma unroll
      for (int m=0;m<4;m++)    a0[m]  = *(const bf16x8v*)&Al[nxt][0][(wm<<7)+(m<<4)+r0][rc];
    }
    __builtin_amdgcn_sched_barrier(0);
    __builtin_amdgcn_s_setprio(1);
    #pragma unroll
    for (int m=0;m<4;m++)
      #pragma unroll
      for (int ni=0;ni<4;ni++)
        acc[4+m][ni] = __builtin_amdgcn_mfma_f32_16x16x32_bf16(a1[m], bv1[ni], acc[4+m][ni], 0, 0, 0);
    __builtin_amdgcn_s_setprio(0);
    asm volatile("s_waitcnt lgkmcnt(0)" ::: "memory");
  }

  float* outF = (float*)out;
  __hip_bfloat16* outH = (__hip_bfloat16*)out;
  const int q = lane >> 4;
  float bia[4];
  #pragma unroll
  for (int ni=0;ni<4;ni++) bia[ni] = bias[colBase + (wn<<6) + (ni<<4) + r0];
  #pragma unroll
  for (int mi=0;mi<8;mi++){
    const int rb = rowBase + (wm<<7) + (mi<<4) + (q<<2);
    #pragma unroll
    for (int j=0;j<4;j++){
      const int r = rb + j;
      #pragma unroll
      for (int ni=0;ni<4;ni++){        // ni innermost: adjacent 32B chunks per row
        const int c = colBase + (wn<<6) + (ni<<4) + r0;
        float v = acc[mi][ni][j] + bia[ni];
        if constexpr (RES==1) v += __bfloat162float(res[(size_t)r*rRS + (size_t)(r>>12)*rBP + rOff + c]);
        if constexpr (RELU)   v = fmaxf(v, 0.f);
        if constexpr (OUTF32) outF[(size_t)r*N + c] = v;
        else                  outH[(size_t)r*N + c] = __float2bfloat16(v);
      }
    }
  }
}

// ---------- LayerNorm over last dim (512), one block per row, bf16 out ----------
template<bool INF32>
__global__ __launch_bounds__(256)
void ln_k(const void* __restrict__ xin, const float* __restrict__ g, const float* __restrict__ bta,
          __hip_bfloat16* __restrict__ outB, int bBP, int bOff)
{
  const int row = blockIdx.x, tid = threadIdx.x;
  float x0, x1;
  if constexpr (INF32){
    const float2 xv = ((const float2*)((const float*)xin + (size_t)row*En))[tid];
    x0 = xv.x; x1 = xv.y;
  } else {
    const unsigned u = ((const unsigned*)((const __hip_bfloat16*)xin + (size_t)row*En))[tid];
    x0 = bfu(u & 0xffffu); x1 = bfu(u >> 16);
  }
  float s = x0 + x1, sq = x0*x0 + x1*x1;
  #pragma unroll
  for (int off=32; off; off>>=1){ s += __shfl_down(s, off); sq += __shfl_down(sq, off); }
  __shared__ float red[8];
  const int w = tid >> 6, lane = tid & 63;
  if (lane == 0){ red[w] = s; red[4+w] = sq; }
  __syncthreads();
  s  = red[0]+red[1]+red[2]+red[3];
  sq = red[4]+red[5]+red[6]+red[7];
  const float mu   = s * (1.f/En);
  const float rstd = rsqrtf(sq * (1.f/En) - mu*mu + 1e-5f);
  const float2 gv = ((const float2*)g)[tid];
  const float2 bv = ((const float2*)bta)[tid];
  const float y0 = (x0 - mu)*rstd*gv.x + bv.x;
  const float y1 = (x1 - mu)*rstd*gv.y + bv.y;
  const size_t base = (size_t)row*En + (size_t)(row>>12)*bBP + bOff + tid*2;
  __hip_bfloat162 o; o.x = __float2bfloat16(y0); o.y = __float2bfloat16(y1);
  *(__hip_bfloat162*)(outB + base) = o;
}

// ---------- linear-space chunked scan over gates packed [row][1536] = f | i | h~ ----------
__global__ __launch_bounds__(256)
void scan_phaseA(const __hip_bfloat16* __restrict__ gi,
                 float* __restrict__ Aagg, float* __restrict__ Bagg)
{
  const int gid = blockIdx.x*256 + threadIdx.x;        // (b, c, hp)  hp in [0,256)
  const int hp = gid & 255, c = (gid >> 8) & 127, b = gid >> 15;
  size_t base = ((size_t)b*Sn + (size_t)c*CHc)*1536 + 2*hp;
  float A0 = 1.f, B0 = 0.f, A1 = 1.f, B1 = 0.f;
  for (int j=0;j<CHc;j++){
    const size_t idx = base + (size_t)j*1536;
    const unsigned uf = *(const unsigned*)(gi + idx);
    const unsigned ui = *(const unsigned*)(gi + idx + 512);
    const unsigned uh = *(const unsigned*)(gi + idx + 1024);
    float fp, ig;
    gate_lin(bfu(uf & 0xffffu), bfu(ui & 0xffffu), bfu(uh & 0xffffu), fp, ig);
    A0 *= fp; B0 = fp*B0 + ig;
    gate_lin(bfu(uf >> 16), bfu(ui >> 16), bfu(uh >> 16), fp, ig);
    A1 *= fp; B1 = fp*B1 + ig;
  }
  const int o = ((b*NCc + c) << 8) + hp;               // float2 index
  ((float2*)Aagg)[o] = make_float2(A0, A1);
  ((float2*)Bagg)[o] = make_float2(B0, B1);
}

__global__ __launch_bounds__(256)
void scan_phaseB(const float* __restrict__ h0, const float* __restrict__ Aagg,
                 const float* __restrict__ Bagg, float* __restrict__ Vst,
                 float* __restrict__ hlast)
{
  const int gid = blockIdx.x*256 + threadIdx.x;        // b*512 + h
  const int h = gid & 511, b = gid >> 9;
  float v = g_of(h0[gid]);
  for (int c=0;c<NCc;c++){
    const int idx = (b*NCc + c)*Hn + h;
    Vst[idx] = v;
    v = fmaf(Aagg[idx], v, Bagg[idx]);
  }
  hlast[gid] = v;
}

__global__ __launch_bounds__(256)
void scan_phaseC(const __hip_bfloat16* __restrict__ gi, const float* __restrict__ Vst,
                 __hip_bfloat16* __restrict__ hseq)
{
  const int gid = blockIdx.x*256 + threadIdx.x;        // (b, c, hp)
  const int hp = gid & 255, c = (gid >> 8) & 127, b = gid >> 15;
  size_t gbase = ((size_t)b*Sn + (size_t)c*CHc)*1536 + 2*hp;
  size_t obase = ((size_t)b*Sn + (size_t)c*CHc)*Hn  + 2*hp;
  const float2 v2 = ((const float2*)Vst)[((b*NCc + c) << 8) + hp];
  float v0 = v2.x, v1 = v2.y;
  for (int j=0;j<CHc;j++){
    const size_t idx = gbase + (size_t)j*1536;
    const unsigned uf = *(const unsigned*)(gi + idx);
    const unsigned ui = *(const unsigned*)(gi + idx + 512);
    const unsigned uh = *(const unsigned*)(gi + idx + 1024);
    float fp, ig;
    gate_lin(bfu(uf & 0xffffu), bfu(ui & 0xffffu), bfu(uh & 0xffffu), fp, ig);
    v0 = fmaf(fp, v0, ig);
    gate_lin(bfu(uf >> 16), bfu(ui >> 16), bfu(uh >> 16), fp, ig);
    v1 = fmaf(fp, v1, ig);
    __hip_bfloat162 o; o.x = __float2bfloat16(v0); o.y = __float2bfloat16(v1);
    *(__hip_bfloat162*)(hseq + obase + (size_t)j*Hn) = o;
  }
}

// ---------- small utility kernels ----------
__global__ void cvt_f32_bf16(const float* __restrict__ src, __hip_bfloat16* __restrict__ dst, int n){
  const int i = blockIdx.x*256 + threadIdx.x;
  if (i < n) dst[i] = __float2bfloat16(src[i]);
}

// conv_w [O=512][I=512][T=4] f32 -> wcv [O][T*512 + I] bf16
__global__ void conv_pack(const float* __restrict__ src, __hip_bfloat16* __restrict__ dst){
  const int d = blockIdx.x*256 + threadIdx.x;
  const int o = d >> 11, r = d & 2047, tap = r >> 9, i = r & 511;
  dst[d] = __float2bfloat16(src[(o*512 + i)*4 + tap]);
}

__global__ void pad_zero(__hip_bfloat16* __restrict__ padded){
  const int gid = blockIdx.x*256 + threadIdx.x;        // 8*3*512
  if (gid < Bn*3*En){
    const int b = gid / (3*En);
    const int j = gid % (3*En);
    const int which = j >> 9, e = j & 511;
    const int u = (which == 0) ? 0 : (4096 + which);   // rows 0, 4097, 4098
    padded[((size_t)b*(Sn+3) + u)*En + e] = __float2bfloat16(0.f);
  }
}

__global__ void pack_bias3(const float* __restrict__ a, const float* __restrict__ b,
                           const float* __restrict__ c, float* __restrict__ dst){
  const int i = blockIdx.x*256 + threadIdx.x;          // 1536
  if (i < 512)       dst[i] = a[i];
  else if (i < 1024) dst[i] = b[i-512];
  else if (i < 1536) dst[i] = c[i-1024];
}

extern "C" void kernel_launch(void* const* d_in, const int* in_sizes, int n_in,
                              void* d_out, int out_size, void* d_ws, size_t ws_size,
                              hipStream_t stream)
{
  const float* x     = (const float*)d_in[0];
  const float* h0    = (const float*)d_in[1];
  const float* lf_w  = (const float*)d_in[2];
  const float* lf_b  = (const float*)d_in[3];
  const float* li_w  = (const float*)d_in[4];
  const float* li_b  = (const float*)d_in[5];
  const float* lh_w  = (const float*)d_in[6];
  const float* lh_b  = (const float*)d_in[7];
  const float* out_w = (const float*)d_in[8];
  const float* out_b = (const float*)d_in[9];
  const float* conv_w= (const float*)d_in[10];
  const float* conv_b= (const float*)d_in[11];
  const float* ln_g  = (const float*)d_in[12];
  const float* ln_b  = (const float*)d_in[13];
  const float* w1    = (const float*)d_in[14];
  const float* b1    = (const float*)d_in[15];
  const float* w2    = (const float*)d_in[16];
  const float* b2    = (const float*)d_in[17];

  float* outx = (float*)d_out;
  float* outh = outx + (size_t)Mn*En;

  // ---- workspace layout (overlay plan) ----
  const size_t AGG = (size_t)Bn*NCc*Hn*4;              // 2 MB each
  const size_t NEED = 5*SLOT + 3*AGG + 8388608 + 6144;
  if (ws_size < NEED) return;

  char* W = (char*)d_ws;
  __hip_bfloat16* GI   = (__hip_bfloat16*)(W);
  __hip_bfloat16* X2   = (__hip_bfloat16*)(W);
  __hip_bfloat16* G1   = (__hip_bfloat16*)(W + SLOT);
  __hip_bfloat16* X3   = (__hip_bfloat16*)(W + 2*SLOT);
  __hip_bfloat16* HSEQ = (__hip_bfloat16*)(W + 3*SLOT);
  __hip_bfloat16* hmid = (__hip_bfloat16*)(W);
  __hip_bfloat16* XN1  = (__hip_bfloat16*)(W + 4*SLOT);   // later XN3
  float* Aagg = (float*)(W + 5*SLOT);
  float* Bagg = Aagg + (size_t)Bn*NCc*Hn;
  float* Vst  = Bagg + (size_t)Bn*NCc*Hn;
  __hip_bfloat16* wg3  = (__hip_bfloat16*)(Vst + (size_t)Bn*NCc*Hn);
  __hip_bfloat16* wout = wg3  + 1536*512;
  __hip_bfloat16* wcv  = wout + 512*512;
  __hip_bfloat16* wm1  = wcv  + 512*2048;
  __hip_bfloat16* wm2  = wm1  + 2048*512;
  float* bg3 = (float*)(wm2 + 512*2048);

  // weight prep
  cvt_f32_bf16<<<1024, 256, 0, stream>>>(lf_w, wg3,            512*512);
  cvt_f32_bf16<<<1024, 256, 0, stream>>>(li_w, wg3 +  512*512, 512*512);
  cvt_f32_bf16<<<1024, 256, 0, stream>>>(lh_w, wg3 + 1024*512, 512*512);
  cvt_f32_bf16<<<1024, 256, 0, stream>>>(out_w, wout, 512*512);
  cvt_f32_bf16<<<4096, 256, 0, stream>>>(w1, wm1, 2048*512);
  cvt_f32_bf16<<<4096, 256, 0, stream>>>(w2, wm2, 512*2048);
  conv_pack   <<<4096, 256, 0, stream>>>(conv_w, wcv);
  pack_bias3  <<<6,    256, 0, stream>>>(lf_b, li_b, lh_b, bg3);

  // LN1: x(f32) -> XN1 bf16
  ln_k<true><<<Mn, 256, 0, stream>>>(x, ln_g, ln_b, XN1, 0, 0);

  // fused gate GEMM: [Mn,512] x [1536,512]^T -> GI [Mn,1536]   (128 x 6 tiles)
  gemm_bf16<0,false,false><<<768, 512, 0, stream>>>(XN1, wg3, 1536, 512, 512, 0, bg3, nullptr, 0,0,0, GI);

  // linear-space chunked scan -> HSEQ bf16, h_last f32
  scan_phaseA<<<1024, 256, 0, stream>>>(GI, Aagg, Bagg);
  scan_phaseB<<<16,   256, 0, stream>>>(h0, Aagg, Bagg, Vst, outh);
  scan_phaseC<<<1024, 256, 0, stream>>>(GI, Vst, HSEQ);

  // zero pad rows of G1 (after GI is dead — G1 overlays S1)
  pad_zero<<<48, 256, 0, stream>>>(G1);

  // out-proj + residual(XN1) -> X2 bf16   (128 x 2 tiles)
  gemm_bf16<1,false,false><<<256, 512, 0, stream>>>(HSEQ, wout, 512, 512, 512, 0, out_b, XN1, 512, 0, 0, X2);

  // LN2: X2 -> padded G1 (row t -> padded row t+1)
  ln_k<false><<<Mn, 256, 0, stream>>>(X2, ln_g, ln_b, G1, 3*En, En);

  // conv as K=2048 GEMM over padded rows + residual(xn2 from G1) -> X3 bf16
  gemm_bf16<1,false,false><<<256, 512, 0, stream>>>(G1, wcv, 512, 2048, 512, 3*En, conv_b, G1, 512, 3*En, En, X3);

  // LN3: X3 -> XN3 bf16 (reuses XN1 slot)
  ln_k<false><<<Mn, 256, 0, stream>>>(X3, ln_g, ln_b, XN1, 0, 0);

  // MLP: relu(XN3 @ w1^T) -> hmid (128 x 8 tiles);  hmid @ w2^T + XN3 -> outx (f32)
  gemm_bf16<0,true ,false><<<1024, 512, 0, stream>>>(XN1, wm1, 2048, 512, 512, 0, b1, nullptr, 0,0,0, hmid);
  gemm_bf16<1,false,true ><<<256,  512, 0, stream>>>(hmid, wm2, 512, 2048, 2048, 0, b2, XN1, 512, 0, 0, outx);
}

// Round 16
// 501.262 us; speedup vs baseline: 1.0320x; 1.0320x over previous
//
#include <hip/hip_runtime.h>
#include <hip/hip_bf16.h>

typedef __attribute__((ext_vector_type(8))) short bf16x8v;
typedef __attribute__((ext_vector_type(4))) float f32x4v;

#define DEV __device__ __forceinline__

constexpr int Bn = 8, Sn = 4096, En = 512, Hn = 512;
constexpr int Mn = Bn * Sn;          // 32768 rows
constexpr int NCc = 128, CHc = 32;   // scan: 128 chunks of 32
constexpr size_t SLOT = 33579008;    // = 8*4099*512*2 bytes (padded-conv buffer), 4096-aligned

// ---------- math helpers ----------
DEV float bfu(unsigned u){ union{unsigned v; float f;} c; c.v = u << 16; return c.f; }

DEV void gload16(const void* g, void* l){
  __builtin_amdgcn_global_load_lds((const __attribute__((address_space(1))) void*)g,
                                   (__attribute__((address_space(3))) void*)l, 16, 0, 0);
}

// linear-space gates: f' = (1+e^-i)/(2+e^-f+e^-i), i' = (1+e^-f)/(...), g = x>=0? x+.5 : sigmoid(x)
DEV void gate_lin(float f, float i, float hp, float& fp, float& ig){
  const float ef = __expf(-f);
  const float ei = __expf(-i);
  const float rd = 1.f / (2.f + ef + ei);
  fp = (1.f + ei) * rd;
  const float ipv = (1.f + ef) * rd;
  const float g = (hp >= 0.f) ? (hp + 0.5f) : (1.f / (1.f + __expf(-hp)));
  ig = ipv * g;
}

DEV float g_of(float x){ return (x >= 0.f) ? (x + 0.5f) : (1.f / (1.f + __expf(-x))); }

// ---------- bf16 MFMA GEMM, 256x128 tile, BK=32, 8 waves (4Mx2N), 512 thr ----------
// REGIME-CORRECTED RETEST of r11's 2-blocks/CU fine-interleave: r11's null was
// measured under the staging request-rate bound (fixed in r14 -> +13%), so its
// occupancy mechanism never got a clean test. This kernel = r11's structure
// (3-buffer 72KB LDS -> 2 blocks/CU; 2 phases/tile with 8 MFMA each; stage-A@p0,
// stage-B@p1; vmcnt(3) keeps tile t+2's 3 loads in flight; vmcnt(0) tail) with
// r14's COALESCED staging (4 lanes cover one row's 64B line; involutive
// chunk-XOR cs=cp^((row>>1)&3) on both global source and ds_read address).
// Mechanism: two desynchronized blocks per CU let one block's MFMA cluster fill
// the other's ds_read/barrier wait (m114) — ceiling max(2xMFMA, 2xLDS) ~ 1240cy
// per window vs the measured serialized 2x1770.
// C[M,N] = A(row-mapped)[M,K] * Bw[N,K]^T + bias
// RES: 0 none, 1 add bf16 residual at res[r*rRS + (r>>12)*rBP + rOff + c]
template<int RES, bool RELU, bool OUTF32>
__global__ __launch_bounds__(512, 4)
void gemm_bf16(const __hip_bfloat16* __restrict__ A,
               const __hip_bfloat16* __restrict__ Bw,
               int N, int K, int aRS, int aBP,
               const float* __restrict__ bias,
               const __hip_bfloat16* __restrict__ res, int rRS, int rBP, int rOff,
               void* __restrict__ out)
{
  __shared__ __align__(16) __hip_bfloat16 Al[3][256][32];   // 48 KB
  __shared__ __align__(16) __hip_bfloat16 Bl[3][128][32];   // 24 KB
  const int tid  = threadIdx.x;
  const int lane = tid & 63;
  const int w    = tid >> 6;            // 0..7
  const int ntn  = N >> 7;
  // T1: XCD-aware bijective swizzle (all grids are multiples of 8)
  const int nwg = gridDim.x;
  int wg = blockIdx.x;
  if ((nwg & 7) == 0) wg = ((wg & 7) * (nwg >> 3)) + (wg >> 3);
  const int bm = wg / ntn, bn = wg % ntn;
  const int rowBase = bm << 8, colBase = bn << 7;
  const int wm = w >> 1, wn = w & 1;    // 4 x 2 wave grid; wave tile 64x64
  const int r0 = lane & 15, kc = lane >> 4;
  const int rc = (kc ^ ((r0 >> 1) & 3)) << 3;   // XOR'd chunk offset within [32k] row

  f32x4v acc[4][4];
  #pragma unroll
  for (int i=0;i<4;i++)
    #pragma unroll
    for (int j=0;j<4;j++)
      #pragma unroll
      for (int q=0;q<4;q++) acc[i][j][q] = 0.f;

  // coalesced staging slots: slot s -> row=s>>2, cp=s&3; src chunk cs=cp^((row>>1)&3)
  // A: 1024 slots (2/thread: rows 0..127 then 128..255); B: 512 slots (1/thread)
  const int ar0 = tid >> 2, acp = tid & 3;
  const int ar1 = 128 + ar0;
  const int acs0 = acp ^ ((ar0 >> 1) & 3);
  const int acs1 = acp ^ ((ar1 >> 1) & 3);
  const int rg0 = rowBase + ar0, rg1 = rowBase + ar1;
  const size_t aoff0 = (size_t)rg0*aRS + (size_t)(rg0>>12)*aBP + (acs0<<3);
  const size_t aoff1 = (size_t)rg1*aRS + (size_t)(rg1>>12)*aBP + (acs1<<3);
  const size_t boff  = (size_t)(colBase + ar0)*K + ((acp ^ ((ar0>>1)&3))<<3);

  auto stageA = [&](int buf, int t){
    const int ke = t << 5;
    gload16(A + aoff0 + ke, &Al[buf][ar0][acp<<3]);
    gload16(A + aoff1 + ke, &Al[buf][ar1][acp<<3]);
  };
  auto stageB = [&](int buf, int t){
    gload16(Bw + boff + (t<<5), &Bl[buf][ar0][acp<<3]);
  };

  const int NT = K >> 5;                // 16 (K=512) or 64 (K=2048)

  // prologue: stage tiles 0 and 1; tile 0 must land (tile 1's 3 stay in flight)
  stageA(0,0); stageB(0,0); stageA(1,1); stageB(1,1);
  asm volatile("s_waitcnt vmcnt(3)" ::: "memory");
  __builtin_amdgcn_s_barrier();

  int cur = 0;
  for (int t=0; t<NT; t++){
    int nb = cur + 2; if (nb >= 3) nb -= 3;
    const bool pre = (t+2 < NT);
    bf16x8v bfv[4], af[2];
    // ---- phase 0: m-frags 0,1 ----
    #pragma unroll
    for (int ni=0;ni<4;ni++) bfv[ni] = *(const bf16x8v*)&Bl[cur][(wn<<6)+(ni<<4)+r0][rc];
    af[0] = *(const bf16x8v*)&Al[cur][(wm<<6)+r0][rc];
    af[1] = *(const bf16x8v*)&Al[cur][(wm<<6)+16+r0][rc];
    if (pre) stageA(nb, t+2);
    __builtin_amdgcn_s_barrier();
    __builtin_amdgcn_s_setprio(1);
    #pragma unroll
    for (int m=0;m<2;m++)
      #pragma unroll
      for (int ni=0;ni<4;ni++)
        acc[m][ni] = __builtin_amdgcn_mfma_f32_16x16x32_bf16(af[m], bfv[ni], acc[m][ni], 0, 0, 0);
    __builtin_amdgcn_s_setprio(0);
    __builtin_amdgcn_s_barrier();
    // ---- phase 1: m-frags 2,3 ----
    af[0] = *(const bf16x8v*)&Al[cur][(wm<<6)+32+r0][rc];
    af[1] = *(const bf16x8v*)&Al[cur][(wm<<6)+48+r0][rc];
    if (pre) stageB(nb, t+2);
    if (pre) asm volatile("s_waitcnt vmcnt(3)" ::: "memory");
    else     asm volatile("s_waitcnt vmcnt(0)" ::: "memory");
    __builtin_amdgcn_s_barrier();
    __builtin_amdgcn_s_setprio(1);
    #pragma unroll
    for (int m=0;m<2;m++)
      #pragma unroll
      for (int ni=0;ni<4;ni++)
        acc[2+m][ni] = __builtin_amdgcn_mfma_f32_16x16x32_bf16(af[m], bfv[ni], acc[2+m][ni], 0, 0, 0);
    __builtin_amdgcn_s_setprio(0);
    __builtin_amdgcn_s_barrier();
    cur = (cur + 1 == 3) ? 0 : cur + 1;
  }

  float* outF = (float*)out;
  __hip_bfloat16* outH = (__hip_bfloat16*)out;
  const int q = lane >> 4;
  float bia[4];
  #pragma unroll
  for (int ni=0;ni<4;ni++) bia[ni] = bias[colBase + (wn<<6) + (ni<<4) + r0];
  #pragma unroll
  for (int mi=0;mi<4;mi++){
    const int rb = rowBase + (wm<<6) + (mi<<4) + (q<<2);
    #pragma unroll
    for (int j=0;j<4;j++){
      const int r = rb + j;
      #pragma unroll
      for (int ni=0;ni<4;ni++){        // ni innermost: adjacent 32B chunks per row
        const int c = colBase + (wn<<6) + (ni<<4) + r0;
        float v = acc[mi][ni][j] + bia[ni];
        if constexpr (RES==1) v += __bfloat162float(res[(size_t)r*rRS + (size_t)(r>>12)*rBP + rOff + c]);
        if constexpr (RELU)   v = fmaxf(v, 0.f);
        if constexpr (OUTF32) outF[(size_t)r*N + c] = v;
        else                  outH[(size_t)r*N + c] = __float2bfloat16(v);
      }
    }
  }
}

// ---------- LayerNorm over last dim (512), one block per row, bf16 out ----------
template<bool INF32>
__global__ __launch_bounds__(256)
void ln_k(const void* __restrict__ xin, const float* __restrict__ g, const float* __restrict__ bta,
          __hip_bfloat16* __restrict__ outB, int bBP, int bOff)
{
  const int row = blockIdx.x, tid = threadIdx.x;
  float x0, x1;
  if constexpr (INF32){
    const float2 xv = ((const float2*)((const float*)xin + (size_t)row*En))[tid];
    x0 = xv.x; x1 = xv.y;
  } else {
    const unsigned u = ((const unsigned*)((const __hip_bfloat16*)xin + (size_t)row*En))[tid];
    x0 = bfu(u & 0xffffu); x1 = bfu(u >> 16);
  }
  float s = x0 + x1, sq = x0*x0 + x1*x1;
  #pragma unroll
  for (int off=32; off; off>>=1){ s += __shfl_down(s, off); sq += __shfl_down(sq, off); }
  __shared__ float red[8];
  const int w = tid >> 6, lane = tid & 63;
  if (lane == 0){ red[w] = s; red[4+w] = sq; }
  __syncthreads();
  s  = red[0]+red[1]+red[2]+red[3];
  sq = red[4]+red[5]+red[6]+red[7];
  const float mu   = s * (1.f/En);
  const float rstd = rsqrtf(sq * (1.f/En) - mu*mu + 1e-5f);
  const float2 gv = ((const float2*)g)[tid];
  const float2 bv = ((const float2*)bta)[tid];
  const float y0 = (x0 - mu)*rstd*gv.x + bv.x;
  const float y1 = (x1 - mu)*rstd*gv.y + bv.y;
  const size_t base = (size_t)row*En + (size_t)(row>>12)*bBP + bOff + tid*2;
  __hip_bfloat162 o; o.x = __float2bfloat16(y0); o.y = __float2bfloat16(y1);
  *(__hip_bfloat162*)(outB + base) = o;
}

// ---------- linear-space chunked scan over gates packed [row][1536] = f | i | h~ ----------
__global__ __launch_bounds__(256)
void scan_phaseA(const __hip_bfloat16* __restrict__ gi,
                 float* __restrict__ Aagg, float* __restrict__ Bagg)
{
  const int gid = blockIdx.x*256 + threadIdx.x;        // (b, c, hp)  hp in [0,256)
  const int hp = gid & 255, c = (gid >> 8) & 127, b = gid >> 15;
  size_t base = ((size_t)b*Sn + (size_t)c*CHc)*1536 + 2*hp;
  float A0 = 1.f, B0 = 0.f, A1 = 1.f, B1 = 0.f;
  for (int j=0;j<CHc;j++){
    const size_t idx = base + (size_t)j*1536;
    const unsigned uf = *(const unsigned*)(gi + idx);
    const unsigned ui = *(const unsigned*)(gi + idx + 512);
    const unsigned uh = *(const unsigned*)(gi + idx + 1024);
    float fp, ig;
    gate_lin(bfu(uf & 0xffffu), bfu(ui & 0xffffu), bfu(uh & 0xffffu), fp, ig);
    A0 *= fp; B0 = fp*B0 + ig;
    gate_lin(bfu(uf >> 16), bfu(ui >> 16), bfu(uh >> 16), fp, ig);
    A1 *= fp; B1 = fp*B1 + ig;
  }
  const int o = ((b*NCc + c) << 8) + hp;               // float2 index
  ((float2*)Aagg)[o] = make_float2(A0, A1);
  ((float2*)Bagg)[o] = make_float2(B0, B1);
}

__global__ __launch_bounds__(256)
void scan_phaseB(const float* __restrict__ h0, const float* __restrict__ Aagg,
                 const float* __restrict__ Bagg, float* __restrict__ Vst,
                 float* __restrict__ hlast)
{
  const int gid = blockIdx.x*256 + threadIdx.x;        // b*512 + h
  const int h = gid & 511, b = gid >> 9;
  float v = g_of(h0[gid]);
  for (int c=0;c<NCc;c++){
    const int idx = (b*NCc + c)*Hn + h;
    Vst[idx] = v;
    v = fmaf(Aagg[idx], v, Bagg[idx]);
  }
  hlast[gid] = v;
}

__global__ __launch_bounds__(256)
void scan_phaseC(const __hip_bfloat16* __restrict__ gi, const float* __restrict__ Vst,
                 __hip_bfloat16* __restrict__ hseq)
{
  const int gid = blockIdx.x*256 + threadIdx.x;        // (b, c, hp)
  const int hp = gid & 255, c = (gid >> 8) & 127, b = gid >> 15;
  size_t gbase = ((size_t)b*Sn + (size_t)c*CHc)*1536 + 2*hp;
  size_t obase = ((size_t)b*Sn + (size_t)c*CHc)*Hn  + 2*hp;
  const float2 v2 = ((const float2*)Vst)[((b*NCc + c) << 8) + hp];
  float v0 = v2.x, v1 = v2.y;
  for (int j=0;j<CHc;j++){
    const size_t idx = gbase + (size_t)j*1536;
    const unsigned uf = *(const unsigned*)(gi + idx);
    const unsigned ui = *(const unsigned*)(gi + idx + 512);
    const unsigned uh = *(const unsigned*)(gi + idx + 1024);
    float fp, ig;
    gate_lin(bfu(uf & 0xffffu), bfu(ui & 0xffffu), bfu(uh & 0xffffu), fp, ig);
    v0 = fmaf(fp, v0, ig);
    gate_lin(bfu(uf >> 16), bfu(ui >> 16), bfu(uh >> 16), fp, ig);
    v1 = fmaf(fp, v1, ig);
    __hip_bfloat162 o; o.x = __float2bfloat16(v0); o.y = __float2bfloat16(v1);
    *(__hip_bfloat162*)(hseq + obase + (size_t)j*Hn) = o;
  }
}

// ---------- small utility kernels ----------
__global__ void cvt_f32_bf16(const float* __restrict__ src, __hip_bfloat16* __restrict__ dst, int n){
  const int i = blockIdx.x*256 + threadIdx.x;
  if (i < n) dst[i] = __float2bfloat16(src[i]);
}

// conv_w [O=512][I=512][T=4] f32 -> wcv [O][T*512 + I] bf16
__global__ void conv_pack(const float* __restrict__ src, __hip_bfloat16* __restrict__ dst){
  const int d = blockIdx.x*256 + threadIdx.x;
  const int o = d >> 11, r = d & 2047, tap = r >> 9, i = r & 511;
  dst[d] = __float2bfloat16(src[(o*512 + i)*4 + tap]);
}

__global__ void pad_zero(__hip_bfloat16* __restrict__ padded){
  const int gid = blockIdx.x*256 + threadIdx.x;        // 8*3*512
  if (gid < Bn*3*En){
    const int b = gid / (3*En);
    const int j = gid % (3*En);
    const int which = j >> 9, e = j & 511;
    const int u = (which == 0) ? 0 : (4096 + which);   // rows 0, 4097, 4098
    padded[((size_t)b*(Sn+3) + u)*En + e] = __float2bfloat16(0.f);
  }
}

__global__ void pack_bias3(const float* __restrict__ a, const float* __restrict__ b,
                           const float* __restrict__ c, float* __restrict__ dst){
  const int i = blockIdx.x*256 + threadIdx.x;          // 1536
  if (i < 512)       dst[i] = a[i];
  else if (i < 1024) dst[i] = b[i-512];
  else if (i < 1536) dst[i] = c[i-1024];
}

extern "C" void kernel_launch(void* const* d_in, const int* in_sizes, int n_in,
                              void* d_out, int out_size, void* d_ws, size_t ws_size,
                              hipStream_t stream)
{
  const float* x     = (const float*)d_in[0];
  const float* h0    = (const float*)d_in[1];
  const float* lf_w  = (const float*)d_in[2];
  const float* lf_b  = (const float*)d_in[3];
  const float* li_w  = (const float*)d_in[4];
  const float* li_b  = (const float*)d_in[5];
  const float* lh_w  = (const float*)d_in[6];
  const float* lh_b  = (const float*)d_in[7];
  const float* out_w = (const float*)d_in[8];
  const float* out_b = (const float*)d_in[9];
  const float* conv_w= (const float*)d_in[10];
  const float* conv_b= (const float*)d_in[11];
  const float* ln_g  = (const float*)d_in[12];
  const float* ln_b  = (const float*)d_in[13];
  const float* w1    = (const float*)d_in[14];
  const float* b1    = (const float*)d_in[15];
  const float* w2    = (const float*)d_in[16];
  const float* b2    = (const float*)d_in[17];

  float* outx = (float*)d_out;
  float* outh = outx + (size_t)Mn*En;

  // ---- workspace layout (overlay plan) ----
  const size_t AGG = (size_t)Bn*NCc*Hn*4;              // 2 MB each
  const size_t NEED = 5*SLOT + 3*AGG + 8388608 + 6144;
  if (ws_size < NEED) return;

  char* W = (char*)d_ws;
  __hip_bfloat16* GI   = (__hip_bfloat16*)(W);
  __hip_bfloat16* X2   = (__hip_bfloat16*)(W);
  __hip_bfloat16* G1   = (__hip_bfloat16*)(W + SLOT);
  __hip_bfloat16* X3   = (__hip_bfloat16*)(W + 2*SLOT);
  __hip_bfloat16* HSEQ = (__hip_bfloat16*)(W + 3*SLOT);
  __hip_bfloat16* hmid = (__hip_bfloat16*)(W);
  __hip_bfloat16* XN1  = (__hip_bfloat16*)(W + 4*SLOT);   // later XN3
  float* Aagg = (float*)(W + 5*SLOT);
  float* Bagg = Aagg + (size_t)Bn*NCc*Hn;
  float* Vst  = Bagg + (size_t)Bn*NCc*Hn;
  __hip_bfloat16* wg3  = (__hip_bfloat16*)(Vst + (size_t)Bn*NCc*Hn);
  __hip_bfloat16* wout = wg3  + 1536*512;
  __hip_bfloat16* wcv  = wout + 512*512;
  __hip_bfloat16* wm1  = wcv  + 512*2048;
  __hip_bfloat16* wm2  = wm1  + 2048*512;
  float* bg3 = (float*)(wm2 + 512*2048);

  // weight prep
  cvt_f32_bf16<<<1024, 256, 0, stream>>>(lf_w, wg3,            512*512);
  cvt_f32_bf16<<<1024, 256, 0, stream>>>(li_w, wg3 +  512*512, 512*512);
  cvt_f32_bf16<<<1024, 256, 0, stream>>>(lh_w, wg3 + 1024*512, 512*512);
  cvt_f32_bf16<<<1024, 256, 0, stream>>>(out_w, wout, 512*512);
  cvt_f32_bf16<<<4096, 256, 0, stream>>>(w1, wm1, 2048*512);
  cvt_f32_bf16<<<4096, 256, 0, stream>>>(w2, wm2, 512*2048);
  conv_pack   <<<4096, 256, 0, stream>>>(conv_w, wcv);
  pack_bias3  <<<6,    256, 0, stream>>>(lf_b, li_b, lh_b, bg3);

  // LN1: x(f32) -> XN1 bf16
  ln_k<true><<<Mn, 256, 0, stream>>>(x, ln_g, ln_b, XN1, 0, 0);

  // fused gate GEMM: [Mn,512] x [1536,512]^T -> GI [Mn,1536]   (128 x 12 tiles)
  gemm_bf16<0,false,false><<<1536, 512, 0, stream>>>(XN1, wg3, 1536, 512, 512, 0, bg3, nullptr, 0,0,0, GI);

  // linear-space chunked scan -> HSEQ bf16, h_last f32
  scan_phaseA<<<1024, 256, 0, stream>>>(GI, Aagg, Bagg);
  scan_phaseB<<<16,   256, 0, stream>>>(h0, Aagg, Bagg, Vst, outh);
  scan_phaseC<<<1024, 256, 0, stream>>>(GI, Vst, HSEQ);

  // zero pad rows of G1 (after GI is dead — G1 overlays S1)
  pad_zero<<<48, 256, 0, stream>>>(G1);

  // out-proj + residual(XN1) -> X2 bf16   (128 x 4 tiles)
  gemm_bf16<1,false,false><<<512, 512, 0, stream>>>(HSEQ, wout, 512, 512, 512, 0, out_b, XN1, 512, 0, 0, X2);

  // LN2: X2 -> padded G1 (row t -> padded row t+1)
  ln_k<false><<<Mn, 256, 0, stream>>>(X2, ln_g, ln_b, G1, 3*En, En);

  // conv as K=2048 GEMM over padded rows + residual(xn2 from G1) -> X3 bf16
  gemm_bf16<1,false,false><<<512, 512, 0, stream>>>(G1, wcv, 512, 2048, 512, 3*En, conv_b, G1, 512, 3*En, En, X3);

  // LN3: X3 -> XN3 bf16 (reuses XN1 slot)
  ln_k<false><<<Mn, 256, 0, stream>>>(X3, ln_g, ln_b, XN1, 0, 0);

  // MLP: relu(XN3 @ w1^T) -> hmid (128 x 16 tiles);  hmid @ w2^T + XN3 -> outx (f32)
  gemm_bf16<0,true ,false><<<2048, 512, 0, stream>>>(XN1, wm1, 2048, 512, 512, 0, b1, nullptr, 0,0,0, hmid);
  gemm_bf16<1,false,true ><<<512,  512, 0, stream>>>(hmid, wm2, 512, 2048, 2048, 0, b2, XN1, 512, 0, 0, outx);
}

// Round 17
// 500.284 us; speedup vs baseline: 1.0340x; 1.0020x over previous
//
#include <hip/hip_runtime.h>
#include <hip/hip_bf16.h>

typedef __attribute__((ext_vector_type(8))) short bf16x8v;
typedef __attribute__((ext_vector_type(4))) float f32x4v;

#define DEV __device__ __forceinline__

constexpr int Bn = 8, Sn = 4096, En = 512, Hn = 512;
constexpr int Mn = Bn * Sn;          // 32768 rows
constexpr int NCc = 128, CHc = 32;   // scan: 128 chunks of 32
constexpr size_t SLOT = 33579008;    // = 8*4099*512*2 bytes (padded-conv buffer), 4096-aligned

// ---------- math helpers ----------
DEV float bfu(unsigned u){ union{unsigned v; float f;} c; c.v = u << 16; return c.f; }

DEV void gload16(const void* g, void* l){
  __builtin_amdgcn_global_load_lds((const __attribute__((address_space(1))) void*)g,
                                   (__attribute__((address_space(3))) void*)l, 16, 0, 0);
}

// linear-space gates: f' = (1+e^-i)/(2+e^-f+e^-i), i' = (1+e^-f)/(...), g = x>=0? x+.5 : sigmoid(x)
DEV void gate_lin(float f, float i, float hp, float& fp, float& ig){
  const float ef = __expf(-f);
  const float ei = __expf(-i);
  const float rd = 1.f / (2.f + ef + ei);
  fp = (1.f + ei) * rd;
  const float ipv = (1.f + ef) * rd;
  const float g = (hp >= 0.f) ? (hp + 0.5f) : (1.f / (1.f + __expf(-hp)));
  ig = ipv * g;
}

DEV float g_of(float x){ return (x >= 0.f) ? (x + 0.5f) : (1.f / (1.f + __expf(-x))); }

// ---------- bf16 MFMA GEMM, 256x128 tile, BK=32, 8 waves (4Mx2N), 512 thr ----------
// r16 (2 blocks/CU, coalesced+XOR staging) with the barrier count cut 4 -> 1
// per K-tile (T3-minimum recipe). Per tile:
//   [read bfv+af01 || stageA(t+2)] -> 8 MFMA (no barrier: own-wave lgkm only)
//   [read af23     || stageB(t+2)] -> vmcnt(3|0)+lgkmcnt(0) -> s_barrier -> 8 MFMA
// Hazard audit (3 buffers, 2-tile lookahead):
//  RAW: tile t+1's 3 stages are the oldest outstanding at the tile-t wait;
//       vmcnt(3) drains them (vmcnt(0) when nothing younger), barrier makes it
//       global -> tile t+1's reads (after the barrier) are safe.
//  WAR: buf cur is overwritten by stages issued at tile t+1 (after the tile-t
//       barrier). Own p0 reads retired via p0 MFMA's lgkm wait; own p1 reads
//       retired via the explicit lgkmcnt(0) before the barrier. Safe.
// Mechanism: with 2 desynchronized blocks/CU and only one lockstep point per
// tile, one block's MFMA fills the other's stage/wait gaps (m114).
// C[M,N] = A(row-mapped)[M,K] * Bw[N,K]^T + bias
// RES: 0 none, 1 add bf16 residual at res[r*rRS + (r>>12)*rBP + rOff + c]
template<int RES, bool RELU, bool OUTF32>
__global__ __launch_bounds__(512, 4)
void gemm_bf16(const __hip_bfloat16* __restrict__ A,
               const __hip_bfloat16* __restrict__ Bw,
               int N, int K, int aRS, int aBP,
               const float* __restrict__ bias,
               const __hip_bfloat16* __restrict__ res, int rRS, int rBP, int rOff,
               void* __restrict__ out)
{
  __shared__ __align__(16) __hip_bfloat16 Al[3][256][32];   // 48 KB
  __shared__ __align__(16) __hip_bfloat16 Bl[3][128][32];   // 24 KB
  const int tid  = threadIdx.x;
  const int lane = tid & 63;
  const int w    = tid >> 6;            // 0..7
  const int ntn  = N >> 7;
  // T1: XCD-aware bijective swizzle (all grids are multiples of 8)
  const int nwg = gridDim.x;
  int wg = blockIdx.x;
  if ((nwg & 7) == 0) wg = ((wg & 7) * (nwg >> 3)) + (wg >> 3);
  const int bm = wg / ntn, bn = wg % ntn;
  const int rowBase = bm << 8, colBase = bn << 7;
  const int wm = w >> 1, wn = w & 1;    // 4 x 2 wave grid; wave tile 64x64
  const int r0 = lane & 15, kc = lane >> 4;
  const int rc = (kc ^ ((r0 >> 1) & 3)) << 3;   // XOR'd chunk offset within [32k] row

  f32x4v acc[4][4];
  #pragma unroll
  for (int i=0;i<4;i++)
    #pragma unroll
    for (int j=0;j<4;j++)
      #pragma unroll
      for (int q=0;q<4;q++) acc[i][j][q] = 0.f;

  // coalesced staging slots: slot s -> row=s>>2, cp=s&3; src chunk cs=cp^((row>>1)&3)
  const int ar0 = tid >> 2, acp = tid & 3;
  const int ar1 = 128 + ar0;
  const int acs0 = acp ^ ((ar0 >> 1) & 3);
  const int acs1 = acp ^ ((ar1 >> 1) & 3);
  const int rg0 = rowBase + ar0, rg1 = rowBase + ar1;
  const size_t aoff0 = (size_t)rg0*aRS + (size_t)(rg0>>12)*aBP + (acs0<<3);
  const size_t aoff1 = (size_t)rg1*aRS + (size_t)(rg1>>12)*aBP + (acs1<<3);
  const size_t boff  = (size_t)(colBase + ar0)*K + (acs0<<3);

  auto stageA = [&](int buf, int t){
    const int ke = t << 5;
    gload16(A + aoff0 + ke, &Al[buf][ar0][acp<<3]);
    gload16(A + aoff1 + ke, &Al[buf][ar1][acp<<3]);
  };
  auto stageB = [&](int buf, int t){
    gload16(Bw + boff + (t<<5), &Bl[buf][ar0][acp<<3]);
  };

  const int NT = K >> 5;                // 16 (K=512) or 64 (K=2048)

  // prologue: stage tiles 0 and 1; tile 0 must land (tile 1's 3 stay in flight)
  stageA(0,0); stageB(0,0); stageA(1,1); stageB(1,1);
  asm volatile("s_waitcnt vmcnt(3)" ::: "memory");
  __builtin_amdgcn_s_barrier();

  int cur = 0;
  for (int t=0; t<NT; t++){
    int nb = cur + 2; if (nb >= 3) nb -= 3;
    const bool pre = (t+2 < NT);
    bf16x8v bfv[4], af[2];
    // ---- p0: frags + stageA, then 8 MFMA (no barrier) ----
    #pragma unroll
    for (int ni=0;ni<4;ni++) bfv[ni] = *(const bf16x8v*)&Bl[cur][(wn<<6)+(ni<<4)+r0][rc];
    af[0] = *(const bf16x8v*)&Al[cur][(wm<<6)+r0][rc];
    af[1] = *(const bf16x8v*)&Al[cur][(wm<<6)+16+r0][rc];
    if (pre) stageA(nb, t+2);
    __builtin_amdgcn_s_setprio(1);
    #pragma unroll
    for (int m=0;m<2;m++)
      #pragma unroll
      for (int ni=0;ni<4;ni++)
        acc[m][ni] = __builtin_amdgcn_mfma_f32_16x16x32_bf16(af[m], bfv[ni], acc[m][ni], 0, 0, 0);
    __builtin_amdgcn_s_setprio(0);
    // ---- p1: frags + stageB, single combined wait + barrier, 8 MFMA ----
    af[0] = *(const bf16x8v*)&Al[cur][(wm<<6)+32+r0][rc];
    af[1] = *(const bf16x8v*)&Al[cur][(wm<<6)+48+r0][rc];
    if (pre) stageB(nb, t+2);
    if (pre) asm volatile("s_waitcnt vmcnt(3) lgkmcnt(0)" ::: "memory");
    else     asm volatile("s_waitcnt vmcnt(0) lgkmcnt(0)" ::: "memory");
    __builtin_amdgcn_s_barrier();
    __builtin_amdgcn_s_setprio(1);
    #pragma unroll
    for (int m=0;m<2;m++)
      #pragma unroll
      for (int ni=0;ni<4;ni++)
        acc[2+m][ni] = __builtin_amdgcn_mfma_f32_16x16x32_bf16(af[m], bfv[ni], acc[2+m][ni], 0, 0, 0);
    __builtin_amdgcn_s_setprio(0);
    cur = (cur + 1 == 3) ? 0 : cur + 1;
  }

  float* outF = (float*)out;
  __hip_bfloat16* outH = (__hip_bfloat16*)out;
  const int q = lane >> 4;
  float bia[4];
  #pragma unroll
  for (int ni=0;ni<4;ni++) bia[ni] = bias[colBase + (wn<<6) + (ni<<4) + r0];
  #pragma unroll
  for (int mi=0;mi<4;mi++){
    const int rb = rowBase + (wm<<6) + (mi<<4) + (q<<2);
    #pragma unroll
    for (int j=0;j<4;j++){
      const int r = rb + j;
      #pragma unroll
      for (int ni=0;ni<4;ni++){        // ni innermost: adjacent 32B chunks per row
        const int c = colBase + (wn<<6) + (ni<<4) + r0;
        float v = acc[mi][ni][j] + bia[ni];
        if constexpr (RES==1) v += __bfloat162float(res[(size_t)r*rRS + (size_t)(r>>12)*rBP + rOff + c]);
        if constexpr (RELU)   v = fmaxf(v, 0.f);
        if constexpr (OUTF32) outF[(size_t)r*N + c] = v;
        else                  outH[(size_t)r*N + c] = __float2bfloat16(v);
      }
    }
  }
}

// ---------- LayerNorm over last dim (512), one block per row, bf16 out ----------
template<bool INF32>
__global__ __launch_bounds__(256)
void ln_k(const void* __restrict__ xin, const float* __restrict__ g, const float* __restrict__ bta,
          __hip_bfloat16* __restrict__ outB, int bBP, int bOff)
{
  const int row = blockIdx.x, tid = threadIdx.x;
  float x0, x1;
  if constexpr (INF32){
    const float2 xv = ((const float2*)((const float*)xin + (size_t)row*En))[tid];
    x0 = xv.x; x1 = xv.y;
  } else {
    const unsigned u = ((const unsigned*)((const __hip_bfloat16*)xin + (size_t)row*En))[tid];
    x0 = bfu(u & 0xffffu); x1 = bfu(u >> 16);
  }
  float s = x0 + x1, sq = x0*x0 + x1*x1;
  #pragma unroll
  for (int off=32; off; off>>=1){ s += __shfl_down(s, off); sq += __shfl_down(sq, off); }
  __shared__ float red[8];
  const int w = tid >> 6, lane = tid & 63;
  if (lane == 0){ red[w] = s; red[4+w] = sq; }
  __syncthreads();
  s  = red[0]+red[1]+red[2]+red[3];
  sq = red[4]+red[5]+red[6]+red[7];
  const float mu   = s * (1.f/En);
  const float rstd = rsqrtf(sq * (1.f/En) - mu*mu + 1e-5f);
  const float2 gv = ((const float2*)g)[tid];
  const float2 bv = ((const float2*)bta)[tid];
  const float y0 = (x0 - mu)*rstd*gv.x + bv.x;
  const float y1 = (x1 - mu)*rstd*gv.y + bv.y;
  const size_t base = (size_t)row*En + (size_t)(row>>12)*bBP + bOff + tid*2;
  __hip_bfloat162 o; o.x = __float2bfloat16(y0); o.y = __float2bfloat16(y1);
  *(__hip_bfloat162*)(outB + base) = o;
}

// ---------- linear-space chunked scan over gates packed [row][1536] = f | i | h~ ----------
__global__ __launch_bounds__(256)
void scan_phaseA(const __hip_bfloat16* __restrict__ gi,
                 float* __restrict__ Aagg, float* __restrict__ Bagg)
{
  const int gid = blockIdx.x*256 + threadIdx.x;        // (b, c, hp)  hp in [0,256)
  const int hp = gid & 255, c = (gid >> 8) & 127, b = gid >> 15;
  size_t base = ((size_t)b*Sn + (size_t)c*CHc)*1536 + 2*hp;
  float A0 = 1.f, B0 = 0.f, A1 = 1.f, B1 = 0.f;
  for (int j=0;j<CHc;j++){
    const size_t idx = base + (size_t)j*1536;
    const unsigned uf = *(const unsigned*)(gi + idx);
    const unsigned ui = *(const unsigned*)(gi + idx + 512);
    const unsigned uh = *(const unsigned*)(gi + idx + 1024);
    float fp, ig;
    gate_lin(bfu(uf & 0xffffu), bfu(ui & 0xffffu), bfu(uh & 0xffffu), fp, ig);
    A0 *= fp; B0 = fp*B0 + ig;
    gate_lin(bfu(uf >> 16), bfu(ui >> 16), bfu(uh >> 16), fp, ig);
    A1 *= fp; B1 = fp*B1 + ig;
  }
  const int o = ((b*NCc + c) << 8) + hp;               // float2 index
  ((float2*)Aagg)[o] = make_float2(A0, A1);
  ((float2*)Bagg)[o] = make_float2(B0, B1);
}

__global__ __launch_bounds__(256)
void scan_phaseB(const float* __restrict__ h0, const float* __restrict__ Aagg,
                 const float* __restrict__ Bagg, float* __restrict__ Vst,
                 float* __restrict__ hlast)
{
  const int gid = blockIdx.x*256 + threadIdx.x;        // b*512 + h
  const int h = gid & 511, b = gid >> 9;
  float v = g_of(h0[gid]);
  for (int c=0;c<NCc;c++){
    const int idx = (b*NCc + c)*Hn + h;
    Vst[idx] = v;
    v = fmaf(Aagg[idx], v, Bagg[idx]);
  }
  hlast[gid] = v;
}

__global__ __launch_bounds__(256)
void scan_phaseC(const __hip_bfloat16* __restrict__ gi, const float* __restrict__ Vst,
                 __hip_bfloat16* __restrict__ hseq)
{
  const int gid = blockIdx.x*256 + threadIdx.x;        // (b, c, hp)
  const int hp = gid & 255, c = (gid >> 8) & 127, b = gid >> 15;
  size_t gbase = ((size_t)b*Sn + (size_t)c*CHc)*1536 + 2*hp;
  size_t obase = ((size_t)b*Sn + (size_t)c*CHc)*Hn  + 2*hp;
  const float2 v2 = ((const float2*)Vst)[((b*NCc + c) << 8) + hp];
  float v0 = v2.x, v1 = v2.y;
  for (int j=0;j<CHc;j++){
    const size_t idx = gbase + (size_t)j*1536;
    const unsigned uf = *(const unsigned*)(gi + idx);
    const unsigned ui = *(const unsigned*)(gi + idx + 512);
    const unsigned uh = *(const unsigned*)(gi + idx + 1024);
    float fp, ig;
    gate_lin(bfu(uf & 0xffffu), bfu(ui & 0xffffu), bfu(uh & 0xffffu), fp, ig);
    v0 = fmaf(fp, v0, ig);
    gate_lin(bfu(uf >> 16), bfu(ui >> 16), bfu(uh >> 16), fp, ig);
    v1 = fmaf(fp, v1, ig);
    __hip_bfloat162 o; o.x = __float2bfloat16(v0); o.y = __float2bfloat16(v1);
    *(__hip_bfloat162*)(hseq + obase + (size_t)j*Hn) = o;
  }
}

// ---------- small utility kernels ----------
__global__ void cvt_f32_bf16(const float* __restrict__ src, __hip_bfloat16* __restrict__ dst, int n){
  const int i = blockIdx.x*256 + threadIdx.x;
  if (i < n) dst[i] = __float2bfloat16(src[i]);
}

// conv_w [O=512][I=512][T=4] f32 -> wcv [O][T*512 + I] bf16
__global__ void conv_pack(const float* __restrict__ src, __hip_bfloat16* __restrict__ dst){
  const int d = blockIdx.x*256 + threadIdx.x;
  const int o = d >> 11, r = d & 2047, tap = r >> 9, i = r & 511;
  dst[d] = __float2bfloat16(src[(o*512 + i)*4 + tap]);
}

__global__ void pad_zero(__hip_bfloat16* __restrict__ padded){
  const int gid = blockIdx.x*256 + threadIdx.x;        // 8*3*512
  if (gid < Bn*3*En){
    const int b = gid / (3*En);
    const int j = gid % (3*En);
    const int which = j >> 9, e = j & 511;
    const int u = (which == 0) ? 0 : (4096 + which);   // rows 0, 4097, 4098
    padded[((size_t)b*(Sn+3) + u)*En + e] = __float2bfloat16(0.f);
  }
}

__global__ void pack_bias3(const float* __restrict__ a, const float* __restrict__ b,
                           const float* __restrict__ c, float* __restrict__ dst){
  const int i = blockIdx.x*256 + threadIdx.x;          // 1536
  if (i < 512)       dst[i] = a[i];
  else if (i < 1024) dst[i] = b[i-512];
  else if (i < 1536) dst[i] = c[i-1024];
}

extern "C" void kernel_launch(void* const* d_in, const int* in_sizes, int n_in,
                              void* d_out, int out_size, void* d_ws, size_t ws_size,
                              hipStream_t stream)
{
  const float* x     = (const float*)d_in[0];
  const float* h0    = (const float*)d_in[1];
  const float* lf_w  = (const float*)d_in[2];
  const float* lf_b  = (const float*)d_in[3];
  const float* li_w  = (const float*)d_in[4];
  const float* li_b  = (const float*)d_in[5];
  const float* lh_w  = (const float*)d_in[6];
  const float* lh_b  = (const float*)d_in[7];
  const float* out_w = (const float*)d_in[8];
  const float* out_b = (const float*)d_in[9];
  const float* conv_w= (const float*)d_in[10];
  const float* conv_b= (const float*)d_in[11];
  const float* ln_g  = (const float*)d_in[12];
  const float* ln_b  = (const float*)d_in[13];
  const float* w1    = (const float*)d_in[14];
  const float* b1    = (const float*)d_in[15];
  const float* w2    = (const float*)d_in[16];
  const float* b2    = (const float*)d_in[17];

  float* outx = (float*)d_out;
  float* outh = outx + (size_t)Mn*En;

  // ---- workspace layout (overlay plan) ----
  const size_t AGG = (size_t)Bn*NCc*Hn*4;              // 2 MB each
  const size_t NEED = 5*SLOT + 3*AGG + 8388608 + 6144;
  if (ws_size < NEED) return;

  char* W = (char*)d_ws;
  __hip_bfloat16* GI   = (__hip_bfloat16*)(W);
  __hip_bfloat16* X2   = (__hip_bfloat16*)(W);
  __hip_bfloat16* G1   = (__hip_bfloat16*)(W + SLOT);
  __hip_bfloat16* X3   = (__hip_bfloat16*)(W + 2*SLOT);
  __hip_bfloat16* HSEQ = (__hip_bfloat16*)(W + 3*SLOT);
  __hip_bfloat16* hmid = (__hip_bfloat16*)(W);
  __hip_bfloat16* XN1  = (__hip_bfloat16*)(W + 4*SLOT);   // later XN3
  float* Aagg = (float*)(W + 5*SLOT);
  float* Bagg = Aagg + (size_t)Bn*NCc*Hn;
  float* Vst  = Bagg + (size_t)Bn*NCc*Hn;
  __hip_bfloat16* wg3  = (__hip_bfloat16*)(Vst + (size_t)Bn*NCc*Hn);
  __hip_bfloat16* wout = wg3  + 1536*512;
  __hip_bfloat16* wcv  = wout + 512*512;
  __hip_bfloat16* wm1  = wcv  + 512*2048;
  __hip_bfloat16* wm2  = wm1  + 2048*512;
  float* bg3 = (float*)(wm2 + 512*2048);

  // weight prep
  cvt_f32_bf16<<<1024, 256, 0, stream>>>(lf_w, wg3,            512*512);
  cvt_f32_bf16<<<1024, 256, 0, stream>>>(li_w, wg3 +  512*512, 512*512);
  cvt_f32_bf16<<<1024, 256, 0, stream>>>(lh_w, wg3 + 1024*512, 512*512);
  cvt_f32_bf16<<<1024, 256, 0, stream>>>(out_w, wout, 512*512);
  cvt_f32_bf16<<<4096, 256, 0, stream>>>(w1, wm1, 2048*512);
  cvt_f32_bf16<<<4096, 256, 0, stream>>>(w2, wm2, 512*2048);
  conv_pack   <<<4096, 256, 0, stream>>>(conv_w, wcv);
  pack_bias3  <<<6,    256, 0, stream>>>(lf_b, li_b, lh_b, bg3);

  // LN1: x(f32) -> XN1 bf16
  ln_k<true><<<Mn, 256, 0, stream>>>(x, ln_g, ln_b, XN1, 0, 0);

  // fused gate GEMM: [Mn,512] x [1536,512]^T -> GI [Mn,1536]   (128 x 12 tiles)
  gemm_bf16<0,false,false><<<1536, 512, 0, stream>>>(XN1, wg3, 1536, 512, 512, 0, bg3, nullptr, 0,0,0, GI);

  // linear-space chunked scan -> HSEQ bf16, h_last f32
  scan_phaseA<<<1024, 256, 0, stream>>>(GI, Aagg, Bagg);
  scan_phaseB<<<16,   256, 0, stream>>>(h0, Aagg, Bagg, Vst, outh);
  scan_phaseC<<<1024, 256, 0, stream>>>(GI, Vst, HSEQ);

  // zero pad rows of G1 (after GI is dead — G1 overlays S1)
  pad_zero<<<48, 256, 0, stream>>>(G1);

  // out-proj + residual(XN1) -> X2 bf16   (128 x 4 tiles)
  gemm_bf16<1,false,false><<<512, 512, 0, stream>>>(HSEQ, wout, 512, 512, 512, 0, out_b, XN1, 512, 0, 0, X2);

  // LN2: X2 -> padded G1 (row t -> padded row t+1)
  ln_k<false><<<Mn, 256, 0, stream>>>(X2, ln_g, ln_b, G1, 3*En, En);

  // conv as K=2048 GEMM over padded rows + residual(xn2 from G1) -> X3 bf16
  gemm_bf16<1,false,false><<<512, 512, 0, stream>>>(G1, wcv, 512, 2048, 512, 3*En, conv_b, G1, 512, 3*En, En, X3);

  // LN3: X3 -> XN3 bf16 (reuses XN1 slot)
  ln_k<false><<<Mn, 256, 0, stream>>>(X3, ln_g, ln_b, XN1, 0, 0);

  // MLP: relu(XN3 @ w1^T) -> hmid (128 x 16 tiles);  hmid @ w2^T + XN3 -> outx (f32)
  gemm_bf16<0,true ,false><<<2048, 512, 0, stream>>>(XN1, wm1, 2048, 512, 512, 0, b1, nullptr, 0,0,0, hmid);
  gemm_bf16<1,false,true ><<<512,  512, 0, stream>>>(hmid, wm2, 512, 2048, 2048, 0, b2, XN1, 512, 0, 0, outx);
}